// Round 3
// baseline (582.860 us; speedup 1.0000x reference)
//
#include <hip/hip_runtime.h>
#include <hip/hip_bf16.h>

#define DIM 256
#define KNN 16
#define SLOPE 0.2f

typedef __hip_bfloat16 bf16;

__device__ __forceinline__ float b2f(bf16 x) { return __bfloat162float(x); }
__device__ __forceinline__ bf16 f2b(float x) { return __float2bfloat16(x); }
__device__ __forceinline__ float leaky(float x) { return x >= 0.f ? x : SLOPE * x; }

// generic load/store in dtype T (float or bf16)
template <typename T> __device__ __forceinline__ float ldT(const T* p, size_t i);
template <> __device__ __forceinline__ float ldT<float>(const float* p, size_t i) { return p[i]; }
template <> __device__ __forceinline__ float ldT<bf16>(const bf16* p, size_t i) { return b2f(p[i]); }
template <typename T> __device__ __forceinline__ void stT(T* p, size_t i, float v);
template <> __device__ __forceinline__ void stT<float>(float* p, size_t i, float v) { p[i] = v; }
template <> __device__ __forceinline__ void stT<bf16>(bf16* p, size_t i, float v) { p[i] = f2b(v); }

// flag semantics: 0 = buffers are bf16, 1 = buffers are f32
template <typename T> __device__ __forceinline__ bool dtype_match(const int* flag) {
    return flag[0] == (sizeof(T) == 4 ? 1 : 0);
}

// Detect input dtype from input_features. If the buffer holds bf16, halfwords at
// even element offsets are valid ~N(0,1) bf16 (biased exponent in [96,140] w.h.p.).
// If it holds f32, those same halfwords are the LOW mantissa bits of floats —
// uniform random — P(8/8 in range) ~ 4e-5.
__global__ void k_detect(const unsigned short* __restrict__ u, int* __restrict__ flag) {
    if (threadIdx.x == 0 && blockIdx.x == 0) {
        int good = 0;
        for (int i = 0; i < 8; ++i) {
            unsigned short h = u[2 * i];
            int e = (h >> 7) & 0xFF;
            if (e == 0 || (e >= 96 && e <= 140)) good++;
        }
        flag[0] = (good >= 7) ? 0 : 1;
    }
}

// Kernel 1: a1 = leaky(in @ w_init + b_init) [N,64] (bf16 ws)
//           resid = leaky(in @ w_res + b_res) [N,256] (dtype T, stored in d_out)
template <typename T>
__global__ __launch_bounds__(256) void k_init_res(
    const int* __restrict__ flag,
    const T* __restrict__ in, const T* __restrict__ w_res,
    const T* __restrict__ b_res, const T* __restrict__ w_init,
    const T* __restrict__ b_init, bf16* __restrict__ a1,
    T* __restrict__ resid, int N)
{
    if (!dtype_match<T>(flag)) return;
    __shared__ float in_s[4][DIM];
    const int t = threadIdx.x;
    const int base = blockIdx.x * 4;

    #pragma unroll
    for (int p = 0; p < 4; ++p)
        in_s[p][t] = ldT<T>(in, (size_t)(base + p) * DIM + t);
    __syncthreads();

    float accR0 = ldT<T>(b_res, t);
    float accR1 = accR0, accR2 = accR0, accR3 = accR0;
    const int colI = t & 63, pI = t >> 6;
    float accI = ldT<T>(b_init, colI);

    for (int k = 0; k < DIM; k += 4) {
        float4 x0 = *(const float4*)&in_s[0][k];
        float4 x1 = *(const float4*)&in_s[1][k];
        float4 x2 = *(const float4*)&in_s[2][k];
        float4 x3 = *(const float4*)&in_s[3][k];
        float4 xi = *(const float4*)&in_s[pI][k];
        const float* px0 = (const float*)&x0;
        const float* px1 = (const float*)&x1;
        const float* px2 = (const float*)&x2;
        const float* px3 = (const float*)&x3;
        const float* pxi = (const float*)&xi;
        #pragma unroll
        for (int j = 0; j < 4; ++j) {
            float w  = ldT<T>(w_res,  (size_t)(k + j) * DIM + t);
            float wi = ldT<T>(w_init, (size_t)(k + j) * 64 + colI);
            accR0 += px0[j] * w;
            accR1 += px1[j] * w;
            accR2 += px2[j] * w;
            accR3 += px3[j] * w;
            accI  += pxi[j] * wi;
        }
    }

    stT<T>(resid, (size_t)(base + 0) * DIM + t, leaky(accR0));
    stT<T>(resid, (size_t)(base + 1) * DIM + t, leaky(accR1));
    stT<T>(resid, (size_t)(base + 2) * DIM + t, leaky(accR2));
    stT<T>(resid, (size_t)(base + 3) * DIM + t, leaky(accR3));
    a1[(size_t)(base + pI) * 64 + colI] = f2b(leaky(accI));
}

// Kernel 2: LFA1. a2[n,0:64] = mean_k leaky(geom @ w_g1 + b_g1); a2[n,64:128] = mean_k a1[idx]
template <typename T>
__global__ __launch_bounds__(256) void k_lfa1(
    const int* __restrict__ flag,
    const T* __restrict__ geom, const int* __restrict__ idx,
    const T* __restrict__ w_g1, const T* __restrict__ b_g1,
    const bf16* __restrict__ a1, bf16* __restrict__ a2, int N)
{
    if (!dtype_match<T>(flag)) return;
    __shared__ float geom_s[2][KNN][4];
    __shared__ int idx_s[2][KNN];
    const int t = threadIdx.x;
    const int n0 = blockIdx.x * 2;

    if (t < 128)
        ((float*)geom_s)[t] = ldT<T>(geom, (size_t)n0 * KNN * 4 + t);
    else if (t < 160)
        ((int*)idx_s)[t - 128] = idx[(size_t)n0 * KNN + (t - 128)];
    __syncthreads();

    const int pt = t >> 7, c = t & 127;
    const int n = n0 + pt;
    float acc = 0.f;
    if (c < 64) {
        float w0 = ldT<T>(w_g1, c),       w1 = ldT<T>(w_g1, 64 + c);
        float w2 = ldT<T>(w_g1, 128 + c), w3 = ldT<T>(w_g1, 192 + c);
        float bb = ldT<T>(b_g1, c);
        #pragma unroll
        for (int k = 0; k < KNN; ++k) {
            float v = geom_s[pt][k][0] * w0 + geom_s[pt][k][1] * w1 +
                      geom_s[pt][k][2] * w2 + geom_s[pt][k][3] * w3 + bb;
            acc += leaky(v);
        }
    } else {
        const int cc = c - 64;
        #pragma unroll
        for (int k = 0; k < KNN; ++k)
            acc += b2f(a1[(size_t)idx_s[pt][k] * 64 + cc]);
    }
    a2[(size_t)n * 128 + c] = f2b(acc * (1.f / 16.f));
}

// Kernel 3 (fused LFA2 + final GEMM + residual add)
template <typename T>
__global__ __launch_bounds__(256) void k_lfa2_fin(
    const int* __restrict__ flag,
    const T* __restrict__ geom, const int* __restrict__ idx,
    const T* __restrict__ w_g2, const T* __restrict__ b_g2,
    const bf16* __restrict__ a2, const T* __restrict__ w_fin,
    const T* __restrict__ b_fin, T* __restrict__ out, int N)
{
    if (!dtype_match<T>(flag)) return;
    __shared__ float a3_s[4][DIM];
    __shared__ float geom_s[4][KNN][4];
    __shared__ int   idx_s[4][KNN];
    const int t = threadIdx.x;
    const int base = blockIdx.x * 4;

    ((float*)geom_s)[t] = ldT<T>(geom, (size_t)base * KNN * 4 + t);
    if (t < 64)
        ((int*)idx_s)[t] = idx[(size_t)base * KNN + t];
    __syncthreads();

    const int pt = t >> 6, c = t & 63;

    {
        float w0a = ldT<T>(w_g2, c),        w1a = ldT<T>(w_g2, 128 + c);
        float w2a = ldT<T>(w_g2, 256 + c),  w3a = ldT<T>(w_g2, 384 + c);
        float w0b = ldT<T>(w_g2, 64 + c),   w1b = ldT<T>(w_g2, 192 + c);
        float w2b = ldT<T>(w_g2, 320 + c),  w3b = ldT<T>(w_g2, 448 + c);
        float ba = ldT<T>(b_g2, c), bb = ldT<T>(b_g2, 64 + c);
        float acca = 0.f, accb = 0.f;
        #pragma unroll
        for (int k = 0; k < KNN; ++k) {
            float g0 = geom_s[pt][k][0], g1 = geom_s[pt][k][1];
            float g2 = geom_s[pt][k][2], g3 = geom_s[pt][k][3];
            acca += leaky(g0 * w0a + g1 * w1a + g2 * w2a + g3 * w3a + ba);
            accb += leaky(g0 * w0b + g1 * w1b + g2 * w2b + g3 * w3b + bb);
        }
        a3_s[pt][c]      = acca * (1.f / 16.f);
        a3_s[pt][64 + c] = accb * (1.f / 16.f);
    }
    {
        float acc0 = 0.f, acc1 = 0.f;
        #pragma unroll
        for (int k = 0; k < KNN; ++k) {
            const bf16* row = a2 + (size_t)idx_s[pt][k] * 128;
            acc0 += b2f(row[c]);
            acc1 += b2f(row[64 + c]);
        }
        a3_s[pt][128 + c] = acc0 * (1.f / 16.f);
        a3_s[pt][192 + c] = acc1 * (1.f / 16.f);
    }
    __syncthreads();

    float acc0 = ldT<T>(b_fin, t);
    float acc1 = acc0, acc2 = acc0, acc3 = acc0;
    for (int k = 0; k < DIM; k += 4) {
        float4 x0 = *(const float4*)&a3_s[0][k];
        float4 x1 = *(const float4*)&a3_s[1][k];
        float4 x2 = *(const float4*)&a3_s[2][k];
        float4 x3 = *(const float4*)&a3_s[3][k];
        const float* px0 = (const float*)&x0;
        const float* px1 = (const float*)&x1;
        const float* px2 = (const float*)&x2;
        const float* px3 = (const float*)&x3;
        #pragma unroll
        for (int j = 0; j < 4; ++j) {
            float w = ldT<T>(w_fin, (size_t)(k + j) * DIM + t);
            acc0 += px0[j] * w;
            acc1 += px1[j] * w;
            acc2 += px2[j] * w;
            acc3 += px3[j] * w;
        }
    }

    #pragma unroll
    for (int p = 0; p < 4; ++p) {
        float a = (p == 0) ? acc0 : (p == 1) ? acc1 : (p == 2) ? acc2 : acc3;
        size_t off = (size_t)(base + p) * DIM + t;
        float r = ldT<T>(out, off);  // resid written by k1
        stT<T>(out, off, leaky(a) + r);
    }
}

extern "C" void kernel_launch(void* const* d_in, const int* in_sizes, int n_in,
                              void* d_out, int out_size, void* d_ws, size_t ws_size,
                              hipStream_t stream) {
    const int* idx = (const int*)d_in[2];
    const int N = in_sizes[0] / DIM;  // 50000

    // ws layout: [0,64) flag; a1 = N*64 bf16 (6.4 MB); a2 = N*128 bf16 (12.8 MB)
    char* ws = (char*)d_ws;
    int* flag = (int*)ws;
    bf16* a1 = (bf16*)(ws + 64);
    bf16* a2 = (bf16*)(ws + 64 + (size_t)N * 64 * sizeof(bf16));

    k_detect<<<1, 1, 0, stream>>>((const unsigned short*)d_in[0], flag);

    const int g1 = N / 4, g2 = N / 2, g3 = N / 4;

    // bf16 variant
    {
        typedef bf16 T;
        k_init_res<T><<<g1, 256, 0, stream>>>(flag, (const T*)d_in[0], (const T*)d_in[3],
            (const T*)d_in[4], (const T*)d_in[5], (const T*)d_in[6], a1, (T*)d_out, N);
        k_lfa1<T><<<g2, 256, 0, stream>>>(flag, (const T*)d_in[1], idx,
            (const T*)d_in[7], (const T*)d_in[8], a1, a2, N);
        k_lfa2_fin<T><<<g3, 256, 0, stream>>>(flag, (const T*)d_in[1], idx,
            (const T*)d_in[9], (const T*)d_in[10], a2, (const T*)d_in[11],
            (const T*)d_in[12], (T*)d_out, N);
    }
    // f32 variant
    {
        typedef float T;
        k_init_res<T><<<g1, 256, 0, stream>>>(flag, (const T*)d_in[0], (const T*)d_in[3],
            (const T*)d_in[4], (const T*)d_in[5], (const T*)d_in[6], a1, (T*)d_out, N);
        k_lfa1<T><<<g2, 256, 0, stream>>>(flag, (const T*)d_in[1], idx,
            (const T*)d_in[7], (const T*)d_in[8], a1, a2, N);
        k_lfa2_fin<T><<<g3, 256, 0, stream>>>(flag, (const T*)d_in[1], idx,
            (const T*)d_in[9], (const T*)d_in[10], a2, (const T*)d_in[11],
            (const T*)d_in[12], (T*)d_out, N);
    }
}

// Round 4
// 292.705 us; speedup vs baseline: 1.9913x; 1.9913x over previous
//
#include <hip/hip_runtime.h>

#define DIM 256
#define KNN 16
#define SLOPE 0.2f

typedef unsigned short u16;
typedef __attribute__((ext_vector_type(8))) unsigned short u16x8;
typedef __attribute__((ext_vector_type(4))) unsigned short u16x4;
typedef __attribute__((ext_vector_type(8))) short s16x8;
typedef __attribute__((ext_vector_type(4))) float f32x4;

__device__ __forceinline__ float leaky(float x) { return x >= 0.f ? x : SLOPE * x; }
// f32 -> bf16 (RNE) as raw u16; inputs are finite (no NaN handling needed)
__device__ __forceinline__ u16 f2bu(float f) {
    unsigned int u = __float_as_uint(f);
    u = (u + 0x7FFFu + ((u >> 16) & 1u)) >> 16;
    return (u16)u;
}
__device__ __forceinline__ float bu2f(u16 h) {
    return __uint_as_float(((unsigned int)h) << 16);
}

// ---------------------------------------------------------------------------
// Prep: transpose + convert weights to bf16 [col][k] layout (k contiguous).
// wT1: 320 rows = w_res cols 0..255 then w_init cols 0..63. wT3: w_fin cols.
// grid = 576 blocks x 256 threads (thread t = k index).
__global__ __launch_bounds__(256) void k_prep(
    const float* __restrict__ w_res, const float* __restrict__ w_init,
    const float* __restrict__ w_fin, u16* __restrict__ wT1, u16* __restrict__ wT3)
{
    const int c = blockIdx.x, t = threadIdx.x;
    if (c < 256)      wT1[c * 256 + t] = f2bu(w_res[t * 256 + c]);
    else if (c < 320) wT1[c * 256 + t] = f2bu(w_init[t * 64 + (c - 256)]);
    else              wT3[(c - 320) * 256 + t] = f2bu(w_fin[t * 256 + (c - 320)]);
}

// ---------------------------------------------------------------------------
// GEMM1 (MFMA): rows=64/block, cols=320 (0..255 -> resid f32 in d_out,
// 256..319 -> a1 bf16 in ws), K=256. A full-K in LDS; B staged per 32-K step.
#define APAD 264  // 256+8 bf16 elems; uniform LDS bank load for b128 frag reads
#define BPAD 40   // 32+8
__global__ __launch_bounds__(256) void k_gemm1(
    const float* __restrict__ in, const u16* __restrict__ wT1,
    const float* __restrict__ b_res, const float* __restrict__ b_init,
    float* __restrict__ resid, u16* __restrict__ a1, int N)
{
    __shared__ u16 A_s[64 * APAD];   // 33792 B
    __shared__ u16 B_s[320 * BPAD];  // 25600 B
    const int t = threadIdx.x;
    const int base = blockIdx.x * 64;

    // stage A: thread t -> row t>>2, 64-k segment t&3; convert f32->bf16
    {
        const int row = t >> 2, seg = t & 3;
        const int grow = min(base + row, N - 1);
        const float* src = in + (size_t)grow * DIM + seg * 64;
        u16* dst = &A_s[row * APAD + seg * 64];
        #pragma unroll
        for (int j = 0; j < 8; ++j) {
            float4 f0 = *(const float4*)(src + j * 8);
            float4 f1 = *(const float4*)(src + j * 8 + 4);
            u16x8 p;
            p[0] = f2bu(f0.x); p[1] = f2bu(f0.y); p[2] = f2bu(f0.z); p[3] = f2bu(f0.w);
            p[4] = f2bu(f1.x); p[5] = f2bu(f1.y); p[6] = f2bu(f1.z); p[7] = f2bu(f1.w);
            *(u16x8*)(dst + j * 8) = p;
        }
    }

    f32x4 acc[4][5];
    #pragma unroll
    for (int i = 0; i < 4; ++i)
        #pragma unroll
        for (int j = 0; j < 5; ++j)
            acc[i][j] = (f32x4){0.f, 0.f, 0.f, 0.f};

    const int w = t >> 6, lane = t & 63;
    const int llow = lane & 15, lhi = lane >> 4;

    for (int ks = 0; ks < 8; ++ks) {
        // prefetch B chunk (1280 16B-chunks / 256 threads = 5 each)
        u16x8 breg[5];
        #pragma unroll
        for (int j = 0; j < 5; ++j) {
            int id = t + 256 * j;
            int col = id >> 2, kg = id & 3;
            breg[j] = *(const u16x8*)(wT1 + col * 256 + ks * 32 + kg * 8);
        }
        __syncthreads();  // prev-step frag reads done (also covers A_s on ks=0)
        #pragma unroll
        for (int j = 0; j < 5; ++j) {
            int id = t + 256 * j;
            int col = id >> 2, kg = id & 3;
            *(u16x8*)(&B_s[col * BPAD + kg * 8]) = breg[j];
        }
        __syncthreads();

        s16x8 afrag[4];
        #pragma unroll
        for (int rt = 0; rt < 4; ++rt)
            afrag[rt] = *(const s16x8*)(&A_s[(rt * 16 + llow) * APAD + ks * 32 + lhi * 8]);
        #pragma unroll
        for (int ci = 0; ci < 5; ++ci) {
            const int ct = w * 5 + ci;
            s16x8 bfrag = *(const s16x8*)(&B_s[(ct * 16 + llow) * BPAD + lhi * 8]);
            #pragma unroll
            for (int rt = 0; rt < 4; ++rt)
                acc[rt][ci] = __builtin_amdgcn_mfma_f32_16x16x32_bf16(
                    afrag[rt], bfrag, acc[rt][ci], 0, 0, 0);
        }
    }

    // epilogue: C map col=lane&15, row=(lane>>4)*4+reg
    #pragma unroll
    for (int ci = 0; ci < 5; ++ci) {
        const int ct = w * 5 + ci;
        const int col = ct * 16 + llow;
        if (col < 256) {
            const float bias = b_res[col];
            #pragma unroll
            for (int rt = 0; rt < 4; ++rt)
                #pragma unroll
                for (int r = 0; r < 4; ++r) {
                    int row = base + rt * 16 + lhi * 4 + r;
                    if (row < N)
                        resid[(size_t)row * DIM + col] = leaky(acc[rt][ci][r] + bias);
                }
        } else {
            const int c2 = col - 256;
            const float bias = b_init[c2];
            #pragma unroll
            for (int rt = 0; rt < 4; ++rt)
                #pragma unroll
                for (int r = 0; r < 4; ++r) {
                    int row = base + rt * 16 + lhi * 4 + r;
                    if (row < N)
                        a1[(size_t)row * 64 + c2] = f2bu(leaky(acc[rt][ci][r] + bias));
                }
        }
    }
}

// ---------------------------------------------------------------------------
// LFA1: 16 points/block. a2[n,0:64] = mean_k leaky(geom@w_g1+b_g1);
// a2[n,64:128] = mean_k a1[idx[n,k],:]. thread = (pt = t>>4, s = t&15), 4 cols each.
__global__ __launch_bounds__(256) void k_lfa1(
    const float* __restrict__ geom, const int* __restrict__ idx,
    const float* __restrict__ w_g1, const float* __restrict__ b_g1,
    const u16* __restrict__ a1, u16* __restrict__ a2, int N)
{
    __shared__ float geom_s[16 * KNN * 4];  // 4 KB
    __shared__ int idx_s[16 * KNN];         // 1 KB
    const int t = threadIdx.x;
    const int base = blockIdx.x * 16;

    {
        size_t off = (size_t)base * 64 + t * 4;
        size_t mx = (size_t)N * 64 - 4;
        if (off > mx) off = mx;
        *(float4*)&geom_s[t * 4] = *(const float4*)(geom + off);
        int io = base * KNN + t;
        if (t < 256) idx_s[t] = idx[min(io, N * KNN - 1)];
    }
    __syncthreads();

    const int pt = t >> 4, s = t & 15;
    const int n = base + pt;

    // geom MLP: cols s*4..s*4+3, weights in regs
    float wr[4][4], bb[4];
    #pragma unroll
    for (int r = 0; r < 4; ++r)
        #pragma unroll
        for (int j = 0; j < 4; ++j)
            wr[r][j] = w_g1[r * 64 + s * 4 + j];
    #pragma unroll
    for (int j = 0; j < 4; ++j) bb[j] = b_g1[s * 4 + j];

    float accM[4] = {0.f, 0.f, 0.f, 0.f};
    const float4* g4 = (const float4*)&geom_s[pt * 64];
    #pragma unroll
    for (int k = 0; k < KNN; ++k) {
        float4 g = g4[k];
        #pragma unroll
        for (int j = 0; j < 4; ++j)
            accM[j] += leaky(g.x * wr[0][j] + g.y * wr[1][j] + g.z * wr[2][j] + g.w * wr[3][j] + bb[j]);
    }

    // gather: cols s*4..s*4+3 of a1
    float accG[4] = {0.f, 0.f, 0.f, 0.f};
    #pragma unroll
    for (int k = 0; k < KNN; ++k) {
        u16x4 u = *(const u16x4*)(a1 + (size_t)idx_s[pt * KNN + k] * 64 + s * 4);
        #pragma unroll
        for (int j = 0; j < 4; ++j) accG[j] += bu2f(u[j]);
    }

    if (n < N) {
        u16x4 pm, pg;
        #pragma unroll
        for (int j = 0; j < 4; ++j) {
            pm[j] = f2bu(accM[j] * 0.0625f);
            pg[j] = f2bu(accG[j] * 0.0625f);
        }
        *(u16x4*)(a2 + (size_t)n * 128 + s * 4) = pm;
        *(u16x4*)(a2 + (size_t)n * 128 + 64 + s * 4) = pg;
    }
}

// ---------------------------------------------------------------------------
// LFA2 + final GEMM fused: 64 points/block. Build a3[64][256] bf16 in LDS
// (cols 0..127 geom-MLP, 128..255 a2-gather), then MFMA vs wT3, epilogue
// leaky(+b_fin) + resid (RMW on d_out which holds resid from k_gemm1).
__global__ __launch_bounds__(256) void k_lfa2_fin(
    const float* __restrict__ geom, const int* __restrict__ idx,
    const float* __restrict__ w_g2, const float* __restrict__ b_g2,
    const u16* __restrict__ a2, const u16* __restrict__ wT3,
    const float* __restrict__ b_fin, float* __restrict__ out, int N)
{
    __shared__ u16 a3_s[64 * APAD];         // 33792 B
    __shared__ u16 B_s[256 * BPAD];         // 20480 B
    __shared__ float geom_s[64 * KNN * 4];  // 16384 B
    __shared__ int idx_s[64 * KNN];         // 4096 B
    const int t = threadIdx.x;
    const int base = blockIdx.x * 64;

    // stage geom + idx (clamped; clamped rows are >= N and never stored)
    {
        size_t mx = (size_t)N * 64 - 4;
        #pragma unroll
        for (int j = 0; j < 4; ++j) {
            size_t off = (size_t)base * 64 + t * 4 + j * 1024;
            if (off > mx) off = mx;
            *(float4*)&geom_s[t * 4 + j * 1024] = *(const float4*)(geom + off);
        }
        int imx = N * KNN - 1;
        #pragma unroll
        for (int j = 0; j < 4; ++j) {
            int off = base * KNN + t + j * 256;
            idx_s[t + j * 256] = idx[min(off, imx)];
        }
    }
    __syncthreads();

    // geom MLP -> a3 cols 0..127. thread = (c = t&127, h = t>>7 -> 32 pts)
    {
        const int c = t & 127, h = t >> 7;
        const float w0 = w_g2[c], w1 = w_g2[128 + c], w2 = w_g2[256 + c],
                    w3 = w_g2[384 + c], bb = b_g2[c];
        for (int p = 0; p < 32; ++p) {
            const int pt = h * 32 + p;
            float acc = 0.f;
            const float4* g4 = (const float4*)&geom_s[pt * 64];
            #pragma unroll
            for (int k = 0; k < KNN; ++k) {
                float4 g = g4[k];
                acc += leaky(g.x * w0 + g.y * w1 + g.z * w2 + g.w * w3 + bb);
            }
            a3_s[pt * APAD + c] = f2bu(acc * 0.0625f);
        }
    }
    // gather -> a3 cols 128..255. thread = (pt = t>>2, q = t&3 -> 32 cols)
    {
        const int pt = t >> 2, q = t & 3;
        float acc[32];
        #pragma unroll
        for (int j = 0; j < 32; ++j) acc[j] = 0.f;
        for (int k = 0; k < KNN; ++k) {
            const u16* row = a2 + (size_t)idx_s[pt * KNN + k] * 128 + q * 32;
            #pragma unroll
            for (int v = 0; v < 4; ++v) {
                u16x8 u = *(const u16x8*)(row + v * 8);
                #pragma unroll
                for (int j = 0; j < 8; ++j) acc[v * 8 + j] += bu2f(u[j]);
            }
        }
        #pragma unroll
        for (int v = 0; v < 4; ++v) {
            u16x8 p;
            #pragma unroll
            for (int j = 0; j < 8; ++j) p[j] = f2bu(acc[v * 8 + j] * 0.0625f);
            *(u16x8*)(&a3_s[pt * APAD + 128 + q * 32 + v * 8]) = p;
        }
    }

    f32x4 acc[4][4];
    #pragma unroll
    for (int i = 0; i < 4; ++i)
        #pragma unroll
        for (int j = 0; j < 4; ++j)
            acc[i][j] = (f32x4){0.f, 0.f, 0.f, 0.f};

    const int w = t >> 6, lane = t & 63;
    const int llow = lane & 15, lhi = lane >> 4;

    for (int ks = 0; ks < 8; ++ks) {
        // B chunks: 1024 / 256 threads = 4 each: thread t -> col t, kg 0..3
        u16x8 breg[4];
        #pragma unroll
        for (int kg = 0; kg < 4; ++kg)
            breg[kg] = *(const u16x8*)(wT3 + t * 256 + ks * 32 + kg * 8);
        __syncthreads();  // a3_s writes done (ks=0) / prev frag reads done
        #pragma unroll
        for (int kg = 0; kg < 4; ++kg)
            *(u16x8*)(&B_s[t * BPAD + kg * 8]) = breg[kg];
        __syncthreads();

        s16x8 afrag[4];
        #pragma unroll
        for (int rt = 0; rt < 4; ++rt)
            afrag[rt] = *(const s16x8*)(&a3_s[(rt * 16 + llow) * APAD + ks * 32 + lhi * 8]);
        #pragma unroll
        for (int ci = 0; ci < 4; ++ci) {
            const int ct = w * 4 + ci;
            s16x8 bfrag = *(const s16x8*)(&B_s[(ct * 16 + llow) * BPAD + lhi * 8]);
            #pragma unroll
            for (int rt = 0; rt < 4; ++rt)
                acc[rt][ci] = __builtin_amdgcn_mfma_f32_16x16x32_bf16(
                    afrag[rt], bfrag, acc[rt][ci], 0, 0, 0);
        }
    }

    #pragma unroll
    for (int ci = 0; ci < 4; ++ci) {
        const int ct = w * 4 + ci;
        const int col = ct * 16 + llow;
        const float bias = b_fin[col];
        #pragma unroll
        for (int rt = 0; rt < 4; ++rt)
            #pragma unroll
            for (int r = 0; r < 4; ++r) {
                int row = base + rt * 16 + lhi * 4 + r;
                if (row < N) {
                    size_t o = (size_t)row * DIM + col;
                    out[o] = leaky(acc[rt][ci][r] + bias) + out[o];
                }
            }
    }
}

// ---------------------------------------------------------------------------
extern "C" void kernel_launch(void* const* d_in, const int* in_sizes, int n_in,
                              void* d_out, int out_size, void* d_ws, size_t ws_size,
                              hipStream_t stream) {
    const float* in    = (const float*)d_in[0];
    const float* geom  = (const float*)d_in[1];
    const int*   idx   = (const int*)d_in[2];
    const float* w_res = (const float*)d_in[3];
    const float* b_res = (const float*)d_in[4];
    const float* w_init= (const float*)d_in[5];
    const float* b_init= (const float*)d_in[6];
    const float* w_g1  = (const float*)d_in[7];
    const float* b_g1  = (const float*)d_in[8];
    const float* w_g2  = (const float*)d_in[9];
    const float* b_g2  = (const float*)d_in[10];
    const float* w_fin = (const float*)d_in[11];
    const float* b_fin = (const float*)d_in[12];
    float* out = (float*)d_out;

    const int N = in_sizes[0] / DIM;  // 50000

    // ws: a1 N*64 bf16 (6.4MB) | a2 N*128 bf16 (12.8MB) | wT1 320*256 bf16 | wT3 256*256 bf16
    char* ws = (char*)d_ws;
    u16* a1  = (u16*)ws;
    u16* a2  = (u16*)(ws + (size_t)N * 64 * 2);
    u16* wT1 = (u16*)(ws + (size_t)N * (64 + 128) * 2);
    u16* wT3 = wT1 + 320 * 256;

    k_prep<<<576, 256, 0, stream>>>(w_res, w_init, w_fin, wT1, wT3);
    k_gemm1<<<(N + 63) / 64, 256, 0, stream>>>(in, wT1, b_res, b_init, out, a1, N);
    k_lfa1<<<(N + 15) / 16, 256, 0, stream>>>(geom, idx, w_g1, b_g1, a1, a2, N);
    k_lfa2_fin<<<(N + 63) / 64, 256, 0, stream>>>(geom, idx, w_g2, b_g2, a2, wT3, b_fin, out, N);
}